// Round 1
// baseline (2205.638 us; speedup 1.0000x reference)
//
#include <hip/hip_runtime.h>
#include <math.h>

#define NN 50000
#define EE 800000
#define TT 6

__device__ __forceinline__ float lrelu(float x){ return x > 0.f ? x : 0.2f*x; }
__device__ __forceinline__ float eluf(float x){ return x > 0.f ? x : expm1f(x); }

// ---------------- CSR build ----------------
__global__ void k_init_counts(int* __restrict__ c){
  int i = blockIdx.x*256 + threadIdx.x;
  if (i < NN) c[i] = 1;          // self loop contributes 1 per node
}

__global__ void k_hist(const int* __restrict__ dst, int* __restrict__ c){
  int i = blockIdx.x*256 + threadIdx.x;
  if (i < EE) atomicAdd(&c[dst[i]], 1);
}

// single-block chunked exclusive scan; counts array becomes the cursor array
__global__ void k_scan(int* __restrict__ cnt_cur, int* __restrict__ rowptr){
  __shared__ int sh[1024];
  __shared__ int s_carry;
  int tid = threadIdx.x;
  if (tid == 0) s_carry = 0;
  __syncthreads();
  for (int base = 0; base < NN; base += 1024){
    int i = base + tid;
    int v = (i < NN) ? cnt_cur[i] : 0;
    int x = v;
    sh[tid] = x; __syncthreads();
    for (int off = 1; off < 1024; off <<= 1){
      int y = (tid >= off) ? sh[tid - off] : 0;
      __syncthreads();
      x += y; sh[tid] = x; __syncthreads();
    }
    int excl = s_carry + x - v;
    if (i < NN){ rowptr[i] = excl; cnt_cur[i] = excl; }
    __syncthreads();
    if (tid == 1023) s_carry += x;
    __syncthreads();
  }
  if (tid == 0) rowptr[NN] = s_carry;
}

__global__ void k_scatter(const int* __restrict__ ei, int* __restrict__ cursor,
                          int* __restrict__ csr){
  int i = blockIdx.x*256 + threadIdx.x;
  if (i < EE){
    int d = ei[EE + i];
    int p = atomicAdd(&cursor[d], 1);
    csr[p] = ei[i];
  } else if (i < EE + NN){
    int v = i - EE;
    int p = atomicAdd(&cursor[v], 1);
    csr[p] = v;              // self loop src = node itself
  }
}

// ---------------- weight preprocessing ----------------
// Was[k][h] = sum_c W[k][h*C+c]*as[h][c]  (a_src = x @ Was since xl = x@W)
__global__ void k_prep(const float* __restrict__ W1, const float* __restrict__ as1,
                       const float* __restrict__ ad1,
                       const float* __restrict__ W2, const float* __restrict__ as2,
                       const float* __restrict__ ad2,
                       const float* __restrict__ cw1, const float* __restrict__ cw2,
                       float* __restrict__ Was1, float* __restrict__ Wad1,
                       float* __restrict__ Was2, float* __restrict__ Wad2,
                       float* __restrict__ cw1t, float* __restrict__ cw2t){
  int tid = threadIdx.x;          // 256
  int k = tid >> 2, h = tid & 3;
  float s1 = 0.f, d1 = 0.f, s2 = 0.f, d2 = 0.f;
  for (int c = 0; c < 16; ++c){
    float w = W1[k*64 + h*16 + c];
    s1 += w * as1[h*16 + c];
    d1 += w * ad1[h*16 + c];
  }
  for (int c = 0; c < 64; ++c){
    float w = W2[k*256 + h*64 + c];
    s2 += w * as2[h*64 + c];
    d2 += w * ad2[h*64 + c];
  }
  Was1[k*4+h] = s1; Wad1[k*4+h] = d1;
  Was2[k*4+h] = s2; Wad2[k*4+h] = d2;
  // transpose conv weights [o][i][k] -> [(i*3+k)][o] for coalesced per-lane reads
  for (int idx = tid; idx < 64*64*3; idx += 256){
    int o = idx & 63, ik = idx >> 6;
    cw1t[idx] = cw1[o*192 + ik];
    cw2t[idx] = cw2[o*192 + ik];
  }
}

// ---------------- GEMM + fused attention-coefficient epilogue ----------------
// C[N,COLS] = A[N,64] @ W[64,COLS]; also a_src/a_dst [N,4] = A @ Was/Wad
template<int COLS>
__global__ void k_gemm_att(const float* __restrict__ A, const float* __restrict__ W,
                           const float* __restrict__ Was, const float* __restrict__ Wad,
                           float* __restrict__ Xl, float* __restrict__ a_src,
                           float* __restrict__ a_dst){
  __shared__ float Alds[16][64];
  int tid = threadIdx.x;
  int r0 = blockIdx.x * 16;
  {
    const float4* A4 = (const float4*)(A + (size_t)r0*64);
    float4 v = A4[tid];
    int r = tid >> 4, k4 = (tid & 15) << 2;
    Alds[r][k4+0] = v.x; Alds[r][k4+1] = v.y;
    Alds[r][k4+2] = v.z; Alds[r][k4+3] = v.w;
  }
  __syncthreads();
  constexpr int RPT = COLS / 16;          // 4 for COLS=64, 16 for COLS=256
  int col = tid % COLS;
  int rbase = (tid / COLS) * RPT;
  float acc[RPT];
#pragma unroll
  for (int r = 0; r < RPT; ++r) acc[r] = 0.f;
  for (int k = 0; k < 64; ++k){
    float w = W[k*COLS + col];
#pragma unroll
    for (int r = 0; r < RPT; ++r) acc[r] += Alds[rbase + r][k] * w;
  }
#pragma unroll
  for (int r = 0; r < RPT; ++r)
    Xl[(size_t)(r0 + rbase + r)*COLS + col] = acc[r];
  // fused a_src/a_dst: 16 rows x 4 heads x {src,dst}
  if (tid < 128){
    int r = tid >> 3, j = tid & 7;
    int h = j & 3;
    const float* Wv = (j < 4) ? Was : Wad;
    float a = 0.f;
    for (int k = 0; k < 64; ++k) a += Alds[r][k] * Wv[k*4 + h];
    if (j < 4) a_src[(r0 + r)*4 + h] = a;
    else       a_dst[(r0 + r)*4 + h] = a;
  }
}

// ---------------- edge softmax + aggregation, layer 1 (H=4, C=16) ----------------
// one wave per node; lane = h*16+c; online softmax per head in registers
__global__ void k_agg1(const float* __restrict__ xl, const float* __restrict__ a_src,
                       const float* __restrict__ a_dst, const float* __restrict__ b1,
                       const int* __restrict__ rowptr, const int* __restrict__ csr,
                       float* __restrict__ h1){
  int lane = threadIdx.x & 63;
  int wid  = threadIdx.x >> 6;
  int n = blockIdx.x*4 + wid;
  int h = lane >> 4;
  float ad = a_dst[n*4 + h];
  int rs = rowptr[n], re = rowptr[n+1];
  float m = -INFINITY, s = 0.f, acc = 0.f;
  for (int j = rs; j < re; ++j){
    int sn = csr[j];
    float e = lrelu(a_src[sn*4 + h] + ad);
    float x = xl[(size_t)sn*64 + lane];
    float mn = fmaxf(m, e);
    float sc = __expf(m - mn);
    float p  = __expf(e - mn);
    s   = s*sc + p;
    acc = acc*sc + p*x;
    m = mn;
  }
  h1[(size_t)n*64 + lane] = eluf(acc/(s + 1e-16f) + b1[lane]);
}

// ---------------- edge softmax + aggregation, layer 2 (H=4, C=64, head-mean) ----
__global__ void k_agg2(const float* __restrict__ xl, const float* __restrict__ a_src,
                       const float* __restrict__ a_dst, const float* __restrict__ b2,
                       const int* __restrict__ rowptr, const int* __restrict__ csr,
                       float* __restrict__ ht){
  int lane = threadIdx.x & 63;
  int wid  = threadIdx.x >> 6;
  int n = blockIdx.x*4 + wid;
  float ad0 = a_dst[n*4+0], ad1 = a_dst[n*4+1], ad2 = a_dst[n*4+2], ad3 = a_dst[n*4+3];
  int rs = rowptr[n], re = rowptr[n+1];
  float m0=-INFINITY,m1=-INFINITY,m2=-INFINITY,m3=-INFINITY;
  float s0=0.f,s1=0.f,s2=0.f,s3=0.f;
  float a0=0.f,a1=0.f,a2=0.f,a3=0.f;
  for (int j = rs; j < re; ++j){
    int sn = csr[j];
    const float* av  = a_src + (size_t)sn*4;
    const float* row = xl + (size_t)sn*256;
    float e0 = lrelu(av[0] + ad0);
    float e1 = lrelu(av[1] + ad1);
    float e2 = lrelu(av[2] + ad2);
    float e3 = lrelu(av[3] + ad3);
    float x0 = row[lane], x1 = row[64+lane], x2 = row[128+lane], x3 = row[192+lane];
    float mn, sc, p;
    mn = fmaxf(m0, e0); sc = __expf(m0-mn); p = __expf(e0-mn);
    s0 = s0*sc + p; a0 = a0*sc + p*x0; m0 = mn;
    mn = fmaxf(m1, e1); sc = __expf(m1-mn); p = __expf(e1-mn);
    s1 = s1*sc + p; a1 = a1*sc + p*x1; m1 = mn;
    mn = fmaxf(m2, e2); sc = __expf(m2-mn); p = __expf(e2-mn);
    s2 = s2*sc + p; a2 = a2*sc + p*x2; m2 = mn;
    mn = fmaxf(m3, e3); sc = __expf(m3-mn); p = __expf(e3-mn);
    s3 = s3*sc + p; a3 = a3*sc + p*x3; m3 = mn;
  }
  float out = 0.25f*(a0/(s0+1e-16f) + a1/(s1+1e-16f) + a2/(s2+1e-16f) + a3/(s3+1e-16f));
  ht[(size_t)n*64 + lane] = eluf(out + b2[lane]);
}

// ---------------- fused temporal conv stack + MLP ----------------
// one wave (block of 64) per node; lane = output channel o
__global__ void k_temporal(const float* __restrict__ ht,
                           const float* __restrict__ cw1t, const float* __restrict__ cb1,
                           const float* __restrict__ g1,   const float* __restrict__ be1,
                           const float* __restrict__ cw2t, const float* __restrict__ cb2,
                           const float* __restrict__ g2,   const float* __restrict__ be2,
                           const float* __restrict__ lw1,  const float* __restrict__ lb1,
                           const float* __restrict__ lw2,  const float* __restrict__ lb2,
                           float* __restrict__ out){
  __shared__ float X[64][8];     // zero-padded time axis: valid at [1..6]
  __shared__ float P[64];
  int o = threadIdx.x;
  int n = blockIdx.x;
  X[o][0] = 0.f; X[o][7] = 0.f;
#pragma unroll
  for (int t = 0; t < 6; ++t) X[o][t+1] = ht[((size_t)t*NN + n)*64 + o];
  __syncthreads();

  float acc[6];
  float bns = g1[o] * rsqrtf(1.f + 1e-5f);
  float cb = cb1[o], be = be1[o];
#pragma unroll
  for (int t = 0; t < 6; ++t) acc[t] = cb;
  for (int i = 0; i < 64; ++i){
    float w0 = cw1t[(i*3+0)*64 + o];
    float w1 = cw1t[(i*3+1)*64 + o];
    float w2 = cw1t[(i*3+2)*64 + o];
    float xr[8];
#pragma unroll
    for (int u = 0; u < 8; ++u) xr[u] = X[i][u];
#pragma unroll
    for (int t = 0; t < 6; ++t) acc[t] += w0*xr[t] + w1*xr[t+1] + w2*xr[t+2];
  }
  __syncthreads();
#pragma unroll
  for (int t = 0; t < 6; ++t) X[o][t+1] = fmaxf(acc[t]*bns + be, 0.f);
  __syncthreads();

  bns = g2[o] * rsqrtf(1.f + 1e-5f);
  cb = cb2[o]; be = be2[o];
#pragma unroll
  for (int t = 0; t < 6; ++t) acc[t] = cb;
  for (int i = 0; i < 64; ++i){
    float w0 = cw2t[(i*3+0)*64 + o];
    float w1 = cw2t[(i*3+1)*64 + o];
    float w2 = cw2t[(i*3+2)*64 + o];
    float xr[8];
#pragma unroll
    for (int u = 0; u < 8; ++u) xr[u] = X[i][u];
#pragma unroll
    for (int t = 0; t < 6; ++t) acc[t] += w0*xr[t] + w1*xr[t+1] + w2*xr[t+2];
  }
  float pooled = 0.f;
#pragma unroll
  for (int t = 0; t < 6; ++t) pooled += fmaxf(acc[t]*bns + be, 0.f);
  pooled *= (1.f/6.f);
  P[o] = pooled;
  __syncthreads();

  float partial = 0.f;
  if (o < 32){
    float a = lb1[o];
    for (int k = 0; k < 64; ++k) a += P[k] * lw1[k*32 + o];
    partial = fmaxf(a, 0.f) * lw2[o];
  }
#pragma unroll
  for (int off = 32; off >= 1; off >>= 1) partial += __shfl_xor(partial, off);
  if (o == 0) out[n] = partial + lb2[0];
}

// ---------------- launch ----------------
extern "C" void kernel_launch(void* const* d_in, const int* in_sizes, int n_in,
                              void* d_out, int out_size, void* d_ws, size_t ws_size,
                              hipStream_t stream) {
  const float* x_seq = (const float*)d_in[0];
  const int*   ei    = (const int*)  d_in[1];
  const float* W1  = (const float*)d_in[2];
  const float* as1 = (const float*)d_in[3];
  const float* ad1 = (const float*)d_in[4];
  const float* b1  = (const float*)d_in[5];
  const float* W2  = (const float*)d_in[6];
  const float* as2 = (const float*)d_in[7];
  const float* ad2 = (const float*)d_in[8];
  const float* b2  = (const float*)d_in[9];
  const float* cw1 = (const float*)d_in[10];
  const float* cb1 = (const float*)d_in[11];
  const float* g1  = (const float*)d_in[12];
  const float* be1 = (const float*)d_in[13];
  const float* cw2 = (const float*)d_in[14];
  const float* cb2 = (const float*)d_in[15];
  const float* g2  = (const float*)d_in[16];
  const float* be2 = (const float*)d_in[17];
  const float* lw1 = (const float*)d_in[18];
  const float* lb1 = (const float*)d_in[19];
  const float* lw2 = (const float*)d_in[20];
  const float* lb2 = (const float*)d_in[21];
  float* out = (float*)d_out;

  char* wp = (char*)d_ws;
  auto alloc = [&](size_t bytes) -> char* {
    char* p = wp; wp += (bytes + 255) & ~(size_t)255; return p;
  };
  int*   rowptr = (int*)  alloc((NN+1)*sizeof(int));
  int*   cursor = (int*)  alloc(NN*sizeof(int));          // also histogram counts
  int*   csr    = (int*)  alloc((size_t)(EE+NN)*sizeof(int));
  float* a_src  = (float*)alloc((size_t)NN*4*sizeof(float));
  float* a_dst  = (float*)alloc((size_t)NN*4*sizeof(float));
  float* xl     = (float*)alloc((size_t)NN*256*sizeof(float));
  float* h1     = (float*)alloc((size_t)NN*64*sizeof(float));
  float* htb    = (float*)alloc((size_t)TT*NN*64*sizeof(float));
  float* Was1   = (float*)alloc(256*sizeof(float));
  float* Wad1   = (float*)alloc(256*sizeof(float));
  float* Was2   = (float*)alloc(256*sizeof(float));
  float* Wad2   = (float*)alloc(256*sizeof(float));
  float* cw1t   = (float*)alloc(64*64*3*sizeof(float));
  float* cw2t   = (float*)alloc(64*64*3*sizeof(float));

  k_init_counts<<<(NN+255)/256, 256, 0, stream>>>(cursor);
  k_hist<<<(EE+255)/256, 256, 0, stream>>>(ei + EE, cursor);
  k_scan<<<1, 1024, 0, stream>>>(cursor, rowptr);
  k_scatter<<<(EE+NN+255)/256, 256, 0, stream>>>(ei, cursor, csr);
  k_prep<<<1, 256, 0, stream>>>(W1, as1, ad1, W2, as2, ad2, cw1, cw2,
                                Was1, Wad1, Was2, Wad2, cw1t, cw2t);

  for (int t = 0; t < TT; ++t){
    k_gemm_att<64><<<NN/16, 256, 0, stream>>>(x_seq + (size_t)t*NN*64, W1, Was1, Wad1,
                                              xl, a_src, a_dst);
    k_agg1<<<NN/4, 256, 0, stream>>>(xl, a_src, a_dst, b1, rowptr, csr, h1);
    k_gemm_att<256><<<NN/16, 256, 0, stream>>>(h1, W2, Was2, Wad2, xl, a_src, a_dst);
    k_agg2<<<NN/4, 256, 0, stream>>>(xl, a_src, a_dst, b2, rowptr, csr,
                                     htb + (size_t)t*NN*64);
  }
  k_temporal<<<NN, 64, 0, stream>>>(htb, cw1t, cb1, g1, be1, cw2t, cb2, g2, be2,
                                    lw1, lb1, lw2, lb2, out);
}

// Round 2
// 1758.859 us; speedup vs baseline: 1.2540x; 1.2540x over previous
//
#include <hip/hip_runtime.h>
#include <math.h>

#define NN 50000
#define EE 800000
#define TT 6

__device__ __forceinline__ float lrelu(float x){ return x > 0.f ? x : 0.2f*x; }
__device__ __forceinline__ float eluf(float x){ return x > 0.f ? x : expm1f(x); }

// ---------------- CSR build ----------------
__global__ void k_init_counts(int* __restrict__ c){
  int i = blockIdx.x*256 + threadIdx.x;
  if (i < NN) c[i] = 1;          // self loop contributes 1 per node
}

__global__ void k_hist(const int* __restrict__ dst, int* __restrict__ c){
  int i = blockIdx.x*256 + threadIdx.x;
  if (i < EE) atomicAdd(&c[dst[i]], 1);
}

// multi-block scan: A (per-block incl scan -> excl + block sums), B (scan sums), C (add)
__global__ void k_scanA(const int* __restrict__ cnt, int* __restrict__ excl,
                        int* __restrict__ bsum){
  __shared__ int sh[1024];
  int tid = threadIdx.x;
  int i = blockIdx.x*1024 + tid;
  int v = (i < NN) ? cnt[i] : 0;
  int x = v;
  sh[tid] = x; __syncthreads();
  for (int off = 1; off < 1024; off <<= 1){
    int y = (tid >= off) ? sh[tid - off] : 0;
    __syncthreads();
    x += y; sh[tid] = x; __syncthreads();
  }
  if (i < NN) excl[i] = x - v;
  if (tid == 1023) bsum[blockIdx.x] = x;
}

__global__ void k_scanB(int* __restrict__ bsum, int nb){
  if (threadIdx.x == 0){
    int run = 0;
    for (int b = 0; b < nb; ++b){ int t = bsum[b]; bsum[b] = run; run += t; }
  }
}

__global__ void k_scanC(const int* __restrict__ excl, const int* __restrict__ bsum,
                        int* __restrict__ rowptr, int* __restrict__ cursor){
  int i = blockIdx.x*1024 + threadIdx.x;
  if (i < NN){
    int v = excl[i] + bsum[blockIdx.x];
    rowptr[i] = v; cursor[i] = v;
  }
  if (i == 0) rowptr[NN] = EE + NN;
}

__global__ void k_scatter(const int* __restrict__ ei, int* __restrict__ cursor,
                          int* __restrict__ csr){
  int i = blockIdx.x*256 + threadIdx.x;
  if (i < EE){
    int d = ei[EE + i];
    int p = atomicAdd(&cursor[d], 1);
    csr[p] = ei[i];
  } else if (i < EE + NN){
    int v = i - EE;
    int p = atomicAdd(&cursor[v], 1);
    csr[p] = v;              // self loop src = node itself
  }
}

// ---------------- weight preprocessing ----------------
__global__ void k_prep(const float* __restrict__ W1, const float* __restrict__ as1,
                       const float* __restrict__ ad1,
                       const float* __restrict__ W2, const float* __restrict__ as2,
                       const float* __restrict__ ad2,
                       const float* __restrict__ cw1, const float* __restrict__ cw2,
                       float* __restrict__ Was1, float* __restrict__ Wad1,
                       float* __restrict__ Was2, float* __restrict__ Wad2,
                       float4* __restrict__ w1p, float4* __restrict__ w2p){
  int tid = threadIdx.x;          // 256
  int k = tid >> 2, h = tid & 3;
  float s1 = 0.f, d1 = 0.f, s2 = 0.f, d2 = 0.f;
  for (int c = 0; c < 16; ++c){
    float w = W1[k*64 + h*16 + c];
    s1 += w * as1[h*16 + c];
    d1 += w * ad1[h*16 + c];
  }
  for (int c = 0; c < 64; ++c){
    float w = W2[k*256 + h*64 + c];
    s2 += w * as2[h*64 + c];
    d2 += w * ad2[h*64 + c];
  }
  Was1[k*4+h] = s1; Wad1[k*4+h] = d1;
  Was2[k*4+h] = s2; Wad2[k*4+h] = d2;
  // pack conv weights [o][i][k] -> float4 at [i*64+o] = (w0,w1,w2,0)
  for (int idx = tid; idx < 64*64; idx += 256){
    int o = idx & 63, i = idx >> 6;
    w1p[idx] = make_float4(cw1[o*192+i*3], cw1[o*192+i*3+1], cw1[o*192+i*3+2], 0.f);
    w2p[idx] = make_float4(cw2[o*192+i*3], cw2[o*192+i*3+1], cw2[o*192+i*3+2], 0.f);
  }
}

// ---------------- GEMM + fused attention-coefficient epilogue ----------------
template<int COLS>
__global__ void k_gemm_att(const float* __restrict__ A, const float* __restrict__ W,
                           const float* __restrict__ Was, const float* __restrict__ Wad,
                           float* __restrict__ Xl, float* __restrict__ a_src,
                           float* __restrict__ a_dst){
  __shared__ float Alds[16][64];
  int tid = threadIdx.x;
  int r0 = blockIdx.x * 16;
  {
    const float4* A4 = (const float4*)(A + (size_t)r0*64);
    float4 v = A4[tid];
    int r = tid >> 4, k4 = (tid & 15) << 2;
    Alds[r][k4+0] = v.x; Alds[r][k4+1] = v.y;
    Alds[r][k4+2] = v.z; Alds[r][k4+3] = v.w;
  }
  __syncthreads();
  constexpr int RPT = COLS / 16;
  int col = tid % COLS;
  int rbase = (tid / COLS) * RPT;
  float acc[RPT];
#pragma unroll
  for (int r = 0; r < RPT; ++r) acc[r] = 0.f;
  for (int k = 0; k < 64; ++k){
    float w = W[k*COLS + col];
#pragma unroll
    for (int r = 0; r < RPT; ++r) acc[r] += Alds[rbase + r][k] * w;
  }
#pragma unroll
  for (int r = 0; r < RPT; ++r)
    Xl[(size_t)(r0 + rbase + r)*COLS + col] = acc[r];
  if (tid < 128){
    int r = tid >> 3, j = tid & 7;
    int h = j & 3;
    const float* Wv = (j < 4) ? Was : Wad;
    float a = 0.f;
    for (int k = 0; k < 64; ++k) a += Alds[r][k] * Wv[k*4 + h];
    if (j < 4) a_src[(r0 + r)*4 + h] = a;
    else       a_dst[(r0 + r)*4 + h] = a;
  }
}

// ---------------- layer 1 aggregation: wave per node, lane = h*16+c --------------
__global__ void k_agg1(const float* __restrict__ xl, const float* __restrict__ a_src,
                       const float* __restrict__ a_dst, const float* __restrict__ b1,
                       const int* __restrict__ rowptr, const int* __restrict__ csr,
                       float* __restrict__ h1){
  int lane = threadIdx.x & 63;
  int wid  = threadIdx.x >> 6;
  int n = blockIdx.x*4 + wid;
  int h = lane >> 4;
  float ad = a_dst[n*4 + h];
  int rs = rowptr[n], re = rowptr[n+1];
  float s = 0.f, acc = 0.f;
  int j = rs;
  for (; j + 4 <= re; j += 4){
    int sn0=csr[j], sn1=csr[j+1], sn2=csr[j+2], sn3=csr[j+3];
    float e0=a_src[sn0*4+h], e1=a_src[sn1*4+h], e2=a_src[sn2*4+h], e3=a_src[sn3*4+h];
    float x0=xl[(size_t)sn0*64+lane], x1=xl[(size_t)sn1*64+lane];
    float x2=xl[(size_t)sn2*64+lane], x3=xl[(size_t)sn3*64+lane];
    float p0=__expf(lrelu(e0+ad)), p1=__expf(lrelu(e1+ad));
    float p2=__expf(lrelu(e2+ad)), p3=__expf(lrelu(e3+ad));
    s += p0; acc += p0*x0;
    s += p1; acc += p1*x1;
    s += p2; acc += p2*x2;
    s += p3; acc += p3*x3;
  }
  for (; j < re; ++j){
    int sn = csr[j];
    float p = __expf(lrelu(a_src[sn*4+h] + ad));
    float x = xl[(size_t)sn*64 + lane];
    s += p; acc += p*x;
  }
  h1[(size_t)n*64 + lane] = eluf(acc/(s + 1e-16f) + b1[lane]);
}

// ---------------- layer 2 aggregation: wave per (node, head) -----------------
__global__ void k_agg2(const float* __restrict__ xl, const float* __restrict__ a_src,
                       const float* __restrict__ a_dst, const float* __restrict__ b2,
                       const int* __restrict__ rowptr, const int* __restrict__ csr,
                       float* __restrict__ ht){
  __shared__ float sacc[4][64];
  int lane = threadIdx.x & 63;
  int h    = threadIdx.x >> 6;     // 4 waves = 4 heads
  int n = blockIdx.x;
  float ad = a_dst[n*4 + h];
  int rs = rowptr[n], re = rowptr[n+1];
  const float* xh = xl + (size_t)h*64 + lane;
  float s = 0.f, acc = 0.f;
  int j = rs;
  for (; j + 4 <= re; j += 4){
    int sn0=csr[j], sn1=csr[j+1], sn2=csr[j+2], sn3=csr[j+3];
    float e0=a_src[sn0*4+h], e1=a_src[sn1*4+h], e2=a_src[sn2*4+h], e3=a_src[sn3*4+h];
    float x0=xh[(size_t)sn0*256], x1=xh[(size_t)sn1*256];
    float x2=xh[(size_t)sn2*256], x3=xh[(size_t)sn3*256];
    float p0=__expf(lrelu(e0+ad)), p1=__expf(lrelu(e1+ad));
    float p2=__expf(lrelu(e2+ad)), p3=__expf(lrelu(e3+ad));
    s += p0; acc += p0*x0;
    s += p1; acc += p1*x1;
    s += p2; acc += p2*x2;
    s += p3; acc += p3*x3;
  }
  for (; j < re; ++j){
    int sn = csr[j];
    float p = __expf(lrelu(a_src[sn*4+h] + ad));
    float x = xh[(size_t)sn*256];
    s += p; acc += p*x;
  }
  sacc[h][lane] = acc/(s + 1e-16f);
  __syncthreads();
  if (h == 0){
    float o = 0.25f*(sacc[0][lane] + sacc[1][lane] + sacc[2][lane] + sacc[3][lane]);
    ht[(size_t)n*64 + lane] = eluf(o + b2[lane]);
  }
}

// ---------------- fused temporal conv stack + MLP, 8 nodes per wave ----------------
__global__ __launch_bounds__(256) void k_temporal(
    const float* __restrict__ htb,
    const float4* __restrict__ w1p, const float* __restrict__ cb1,
    const float* __restrict__ g1,   const float* __restrict__ be1,
    const float4* __restrict__ w2p, const float* __restrict__ cb2,
    const float* __restrict__ g2,   const float* __restrict__ be2,
    const float* __restrict__ lw1,  const float* __restrict__ lb1,
    const float* __restrict__ lw2,  const float* __restrict__ lb2,
    float* __restrict__ out){
  __shared__ float X[4][8][64][8];   // [wave][node][chan][time(padded)] = 64 KB
  int o   = threadIdx.x & 63;
  int wid = threadIdx.x >> 6;
  int nbase = (blockIdx.x*4 + wid)*8;
  float (*Xw)[64][8] = X[wid];

#pragma unroll
  for (int nn = 0; nn < 8; ++nn){
    int n = nbase + nn;
    Xw[nn][o][0] = 0.f; Xw[nn][o][7] = 0.f;
    if (n < NN){
#pragma unroll
      for (int t = 0; t < 6; ++t) Xw[nn][o][t+1] = htb[((size_t)t*NN + n)*64 + o];
    } else {
#pragma unroll
      for (int t = 0; t < 6; ++t) Xw[nn][o][t+1] = 0.f;
    }
  }
  __syncthreads();

  float acc[8][6];
  // ---- conv1 ----
  {
    float c = cb1[o];
#pragma unroll
    for (int nn = 0; nn < 8; ++nn)
#pragma unroll
      for (int t = 0; t < 6; ++t) acc[nn][t] = c;
    for (int i = 0; i < 64; ++i){
      float4 w = w1p[i*64 + o];
#pragma unroll
      for (int nn = 0; nn < 8; ++nn){
        float4 xa = *(const float4*)&Xw[nn][i][0];
        float4 xb = *(const float4*)&Xw[nn][i][4];
        acc[nn][0] += w.x*xa.x + w.y*xa.y + w.z*xa.z;
        acc[nn][1] += w.x*xa.y + w.y*xa.z + w.z*xa.w;
        acc[nn][2] += w.x*xa.z + w.y*xa.w + w.z*xb.x;
        acc[nn][3] += w.x*xa.w + w.y*xb.x + w.z*xb.y;
        acc[nn][4] += w.x*xb.x + w.y*xb.y + w.z*xb.z;
        acc[nn][5] += w.x*xb.y + w.y*xb.z + w.z*xb.w;
      }
    }
    float bns = g1[o]*rsqrtf(1.f + 1e-5f), be = be1[o];
    __syncthreads();
#pragma unroll
    for (int nn = 0; nn < 8; ++nn)
#pragma unroll
      for (int t = 0; t < 6; ++t) Xw[nn][o][t+1] = fmaxf(acc[nn][t]*bns + be, 0.f);
    __syncthreads();
  }
  // ---- conv2 + pool ----
  {
    float c = cb2[o];
#pragma unroll
    for (int nn = 0; nn < 8; ++nn)
#pragma unroll
      for (int t = 0; t < 6; ++t) acc[nn][t] = c;
    for (int i = 0; i < 64; ++i){
      float4 w = w2p[i*64 + o];
#pragma unroll
      for (int nn = 0; nn < 8; ++nn){
        float4 xa = *(const float4*)&Xw[nn][i][0];
        float4 xb = *(const float4*)&Xw[nn][i][4];
        acc[nn][0] += w.x*xa.x + w.y*xa.y + w.z*xa.z;
        acc[nn][1] += w.x*xa.y + w.y*xa.z + w.z*xa.w;
        acc[nn][2] += w.x*xa.z + w.y*xa.w + w.z*xb.x;
        acc[nn][3] += w.x*xa.w + w.y*xb.x + w.z*xb.y;
        acc[nn][4] += w.x*xb.x + w.y*xb.y + w.z*xb.z;
        acc[nn][5] += w.x*xb.y + w.y*xb.z + w.z*xb.w;
      }
    }
    float bns = g2[o]*rsqrtf(1.f + 1e-5f), be = be2[o];
    __syncthreads();
#pragma unroll
    for (int nn = 0; nn < 8; ++nn){
      float pooled = 0.f;
#pragma unroll
      for (int t = 0; t < 6; ++t) pooled += fmaxf(acc[nn][t]*bns + be, 0.f);
      Xw[nn][o][0] = pooled*(1.f/6.f);
    }
    __syncthreads();
  }
  // ---- MLP: lanes 0-31 do node pr*2, lanes 32-63 do node pr*2+1 ----
  {
    int jj   = threadIdx.x & 31;
    int half = (o >> 5);
    float w2 = lw2[jj];
    float lb = lb1[jj];
#pragma unroll
    for (int pr = 0; pr < 4; ++pr){
      int nn = pr*2 + half;
      float a = lb;
      for (int k = 0; k < 64; ++k) a += Xw[nn][k][0] * lw1[k*32 + jj];
      float part = fmaxf(a, 0.f) * w2;
#pragma unroll
      for (int off = 16; off >= 1; off >>= 1) part += __shfl_xor(part, off);
      if (jj == 0){
        int n = nbase + nn;
        if (n < NN) out[n] = part + lb2[0];
      }
    }
  }
}

// ---------------- launch ----------------
extern "C" void kernel_launch(void* const* d_in, const int* in_sizes, int n_in,
                              void* d_out, int out_size, void* d_ws, size_t ws_size,
                              hipStream_t stream) {
  const float* x_seq = (const float*)d_in[0];
  const int*   ei    = (const int*)  d_in[1];
  const float* W1  = (const float*)d_in[2];
  const float* as1 = (const float*)d_in[3];
  const float* ad1 = (const float*)d_in[4];
  const float* b1  = (const float*)d_in[5];
  const float* W2  = (const float*)d_in[6];
  const float* as2 = (const float*)d_in[7];
  const float* ad2 = (const float*)d_in[8];
  const float* b2  = (const float*)d_in[9];
  const float* cw1 = (const float*)d_in[10];
  const float* cb1 = (const float*)d_in[11];
  const float* g1  = (const float*)d_in[12];
  const float* be1 = (const float*)d_in[13];
  const float* cw2 = (const float*)d_in[14];
  const float* cb2 = (const float*)d_in[15];
  const float* g2  = (const float*)d_in[16];
  const float* be2 = (const float*)d_in[17];
  const float* lw1 = (const float*)d_in[18];
  const float* lb1 = (const float*)d_in[19];
  const float* lw2 = (const float*)d_in[20];
  const float* lb2 = (const float*)d_in[21];
  float* out = (float*)d_out;

  char* wp = (char*)d_ws;
  auto alloc = [&](size_t bytes) -> char* {
    char* p = wp; wp += (bytes + 255) & ~(size_t)255; return p;
  };
  int*   counts = (int*)  alloc(NN*sizeof(int));
  int*   excl   = (int*)  alloc(NN*sizeof(int));
  int*   bsum   = (int*)  alloc(64*sizeof(int));
  int*   rowptr = (int*)  alloc((NN+1)*sizeof(int));
  int*   cursor = (int*)  alloc(NN*sizeof(int));
  int*   csr    = (int*)  alloc((size_t)(EE+NN)*sizeof(int));
  float* a_src  = (float*)alloc((size_t)NN*4*sizeof(float));
  float* a_dst  = (float*)alloc((size_t)NN*4*sizeof(float));
  float* xl     = (float*)alloc((size_t)NN*256*sizeof(float));
  float* h1     = (float*)alloc((size_t)NN*64*sizeof(float));
  float* htb    = (float*)alloc((size_t)TT*NN*64*sizeof(float));
  float* Was1   = (float*)alloc(256*sizeof(float));
  float* Wad1   = (float*)alloc(256*sizeof(float));
  float* Was2   = (float*)alloc(256*sizeof(float));
  float* Wad2   = (float*)alloc(256*sizeof(float));
  float4* w1p   = (float4*)alloc(64*64*sizeof(float4));
  float4* w2p   = (float4*)alloc(64*64*sizeof(float4));

  const int NBSCAN = (NN + 1023)/1024;   // 49
  k_init_counts<<<(NN+255)/256, 256, 0, stream>>>(counts);
  k_hist<<<(EE+255)/256, 256, 0, stream>>>(ei + EE, counts);
  k_scanA<<<NBSCAN, 1024, 0, stream>>>(counts, excl, bsum);
  k_scanB<<<1, 64, 0, stream>>>(bsum, NBSCAN);
  k_scanC<<<NBSCAN, 1024, 0, stream>>>(excl, bsum, rowptr, cursor);
  k_scatter<<<(EE+NN+255)/256, 256, 0, stream>>>(ei, cursor, csr);
  k_prep<<<1, 256, 0, stream>>>(W1, as1, ad1, W2, as2, ad2, cw1, cw2,
                                Was1, Wad1, Was2, Wad2, w1p, w2p);

  for (int t = 0; t < TT; ++t){
    k_gemm_att<64><<<NN/16, 256, 0, stream>>>(x_seq + (size_t)t*NN*64, W1, Was1, Wad1,
                                              xl, a_src, a_dst);
    k_agg1<<<NN/4, 256, 0, stream>>>(xl, a_src, a_dst, b1, rowptr, csr, h1);
    k_gemm_att<256><<<NN/16, 256, 0, stream>>>(h1, W2, Was2, Wad2, xl, a_src, a_dst);
    k_agg2<<<NN, 256, 0, stream>>>(xl, a_src, a_dst, b2, rowptr, csr,
                                   htb + (size_t)t*NN*64);
  }
  k_temporal<<<(NN+31)/32, 256, 0, stream>>>(htb, w1p, cb1, g1, be1, w2p, cb2, g2, be2,
                                             lw1, lb1, lw2, lb2, out);
}

// Round 3
// 1733.332 us; speedup vs baseline: 1.2725x; 1.0147x over previous
//
#include <hip/hip_runtime.h>
#include <math.h>

#define NN 50000
#define EE 800000
#define TT 6

__device__ __forceinline__ float lrelu(float x){ return x > 0.f ? x : 0.2f*x; }
__device__ __forceinline__ float eluf(float x){ return x > 0.f ? x : expm1f(x); }

// ---------------- CSR build ----------------
__global__ void k_init_counts(int* __restrict__ c){
  int i = blockIdx.x*256 + threadIdx.x;
  if (i < NN) c[i] = 1;          // self loop contributes 1 per node
}

__global__ void k_hist(const int* __restrict__ dst, int* __restrict__ c){
  int i = blockIdx.x*256 + threadIdx.x;
  if (i < EE) atomicAdd(&c[dst[i]], 1);
}

__global__ void k_scanA(const int* __restrict__ cnt, int* __restrict__ excl,
                        int* __restrict__ bsum){
  __shared__ int sh[1024];
  int tid = threadIdx.x;
  int i = blockIdx.x*1024 + tid;
  int v = (i < NN) ? cnt[i] : 0;
  int x = v;
  sh[tid] = x; __syncthreads();
  for (int off = 1; off < 1024; off <<= 1){
    int y = (tid >= off) ? sh[tid - off] : 0;
    __syncthreads();
    x += y; sh[tid] = x; __syncthreads();
  }
  if (i < NN) excl[i] = x - v;
  if (tid == 1023) bsum[blockIdx.x] = x;
}

__global__ void k_scanB(int* __restrict__ bsum, int nb){
  if (threadIdx.x == 0){
    int run = 0;
    for (int b = 0; b < nb; ++b){ int t = bsum[b]; bsum[b] = run; run += t; }
  }
}

__global__ void k_scanC(const int* __restrict__ excl, const int* __restrict__ bsum,
                        int* __restrict__ rowptr, int* __restrict__ cursor){
  int i = blockIdx.x*1024 + threadIdx.x;
  if (i < NN){
    int v = excl[i] + bsum[blockIdx.x];
    rowptr[i] = v; cursor[i] = v;
  }
  if (i == 0) rowptr[NN] = EE + NN;
}

__global__ void k_scatter(const int* __restrict__ ei, int* __restrict__ cursor,
                          int* __restrict__ csr){
  int i = blockIdx.x*256 + threadIdx.x;
  if (i < EE){
    int d = ei[EE + i];
    int p = atomicAdd(&cursor[d], 1);
    csr[p] = ei[i];
  } else if (i < EE + NN){
    int v = i - EE;
    int p = atomicAdd(&cursor[v], 1);
    csr[p] = v;              // self loop src = node itself
  }
}

// ---------------- weight preprocessing ----------------
__global__ void k_prep(const float* __restrict__ W1, const float* __restrict__ as1,
                       const float* __restrict__ ad1,
                       const float* __restrict__ W2, const float* __restrict__ as2,
                       const float* __restrict__ ad2,
                       const float* __restrict__ cw1, const float* __restrict__ cw2,
                       float* __restrict__ Was1, float* __restrict__ Wad1,
                       float* __restrict__ Was2, float* __restrict__ Wad2,
                       float4* __restrict__ w1p, float4* __restrict__ w2p){
  int tid = threadIdx.x;          // 256
  int k = tid >> 2, h = tid & 3;
  float s1 = 0.f, d1 = 0.f, s2 = 0.f, d2 = 0.f;
  for (int c = 0; c < 16; ++c){
    float w = W1[k*64 + h*16 + c];
    s1 += w * as1[h*16 + c];
    d1 += w * ad1[h*16 + c];
  }
  for (int c = 0; c < 64; ++c){
    float w = W2[k*256 + h*64 + c];
    s2 += w * as2[h*64 + c];
    d2 += w * ad2[h*64 + c];
  }
  Was1[k*4+h] = s1; Wad1[k*4+h] = d1;
  Was2[k*4+h] = s2; Wad2[k*4+h] = d2;
  // pack conv weights [o][i][k] -> float4 at [i*64+o] = (w0,w1,w2,0)
  for (int idx = tid; idx < 64*64; idx += 256){
    int o = idx & 63, i = idx >> 6;
    w1p[idx] = make_float4(cw1[o*192+i*3], cw1[o*192+i*3+1], cw1[o*192+i*3+2], 0.f);
    w2p[idx] = make_float4(cw2[o*192+i*3], cw2[o*192+i*3+1], cw2[o*192+i*3+2], 0.f);
  }
}

// ---------------- GEMM + fused attention-coefficient epilogue ----------------
// A-tile stored TRANSPOSED in LDS: At[k][r] -> main-loop reads are b128 broadcasts
template<int COLS>
__global__ void k_gemm_att(const float* __restrict__ A, const float* __restrict__ W,
                           const float* __restrict__ Was, const float* __restrict__ Wad,
                           float* __restrict__ Xl, float* __restrict__ a_src,
                           float* __restrict__ a_dst){
  __shared__ float At[64][16];
  int tid = threadIdx.x;
  int r0 = blockIdx.x * 16;
  {
    const float4* A4 = (const float4*)(A + (size_t)r0*64);
    float4 v = A4[tid];
    int r = tid >> 4, k4 = (tid & 15) << 2;
    At[k4+0][r] = v.x; At[k4+1][r] = v.y;
    At[k4+2][r] = v.z; At[k4+3][r] = v.w;
  }
  __syncthreads();
  constexpr int RPT = COLS / 16;
  int col = tid % COLS;
  int rbase = (tid / COLS) * RPT;
  float acc[RPT];
#pragma unroll
  for (int r = 0; r < RPT; ++r) acc[r] = 0.f;
  for (int k = 0; k < 64; ++k){
    float w = W[k*COLS + col];
    if constexpr (COLS == 64){
      float4 a4 = *(const float4*)&At[k][rbase];
      acc[0] += a4.x*w; acc[1] += a4.y*w; acc[2] += a4.z*w; acc[3] += a4.w*w;
    } else {
#pragma unroll
      for (int rq = 0; rq < 4; ++rq){
        float4 a4 = *(const float4*)&At[k][rq*4];
        acc[rq*4+0] += a4.x*w; acc[rq*4+1] += a4.y*w;
        acc[rq*4+2] += a4.z*w; acc[rq*4+3] += a4.w*w;
      }
    }
  }
#pragma unroll
  for (int r = 0; r < RPT; ++r)
    Xl[(size_t)(r0 + rbase + r)*COLS + col] = acc[r];
  if (tid < 128){
    int r = tid >> 3, jx = tid & 7;
    int h = jx & 3;
    const float* Wv = (jx < 4) ? Was : Wad;
    float a = 0.f;
    for (int k = 0; k < 64; ++k) a += At[k][r] * Wv[k*4 + h];
    if (jx < 4) a_src[(r0 + r)*4 + h] = a;
    else        a_dst[(r0 + r)*4 + h] = a;
  }
}

// ---------------- layer 1 aggregation: wave per node, lane = h*16+c --------------
__global__ void k_agg1(const float* __restrict__ xl, const float* __restrict__ a_src,
                       const float* __restrict__ a_dst, const float* __restrict__ b1,
                       const int* __restrict__ rowptr, const int* __restrict__ csr,
                       float* __restrict__ h1){
  int lane = threadIdx.x & 63;
  int wid  = threadIdx.x >> 6;
  int n = blockIdx.x*4 + wid;
  int h = lane >> 4;
  float ad = a_dst[n*4 + h];
  int rs = rowptr[n], re = rowptr[n+1];
  float s = 0.f, acc = 0.f;
  int j = rs;
  for (; j + 4 <= re; j += 4){
    int sn0=csr[j], sn1=csr[j+1], sn2=csr[j+2], sn3=csr[j+3];
    float e0=a_src[sn0*4+h], e1=a_src[sn1*4+h], e2=a_src[sn2*4+h], e3=a_src[sn3*4+h];
    float x0=xl[(size_t)sn0*64+lane], x1=xl[(size_t)sn1*64+lane];
    float x2=xl[(size_t)sn2*64+lane], x3=xl[(size_t)sn3*64+lane];
    float p0=__expf(lrelu(e0+ad)), p1=__expf(lrelu(e1+ad));
    float p2=__expf(lrelu(e2+ad)), p3=__expf(lrelu(e3+ad));
    s += p0; acc += p0*x0;
    s += p1; acc += p1*x1;
    s += p2; acc += p2*x2;
    s += p3; acc += p3*x3;
  }
  for (; j < re; ++j){
    int sn = csr[j];
    float p = __expf(lrelu(a_src[sn*4+h] + ad));
    float x = xl[(size_t)sn*64 + lane];
    s += p; acc += p*x;
  }
  h1[(size_t)n*64 + lane] = eluf(acc/(s + 1e-16f) + b1[lane]);
}

// ---------------- layer 2 aggregation: wave per node, ALL 4 heads ---------------
__global__ void k_agg2(const float* __restrict__ xl, const float* __restrict__ a_src,
                       const float* __restrict__ a_dst, const float* __restrict__ b2,
                       const int* __restrict__ rowptr, const int* __restrict__ csr,
                       float* __restrict__ ht){
  int lane = threadIdx.x & 63;
  int wid  = threadIdx.x >> 6;
  int n = blockIdx.x*4 + wid;
  float4 ad = ((const float4*)a_dst)[n];
  int rs = rowptr[n], re = rowptr[n+1];
  const float* xb = xl + lane;
  float s0=0.f,s1=0.f,s2=0.f,s3=0.f;
  float a0=0.f,a1=0.f,a2=0.f,a3=0.f;
  int j = rs;
  for (; j + 2 <= re; j += 2){
    int sna = csr[j], snb = csr[j+1];
    float4 ea = ((const float4*)a_src)[sna];
    float4 eb = ((const float4*)a_src)[snb];
    const float* ra = xb + (size_t)sna*256;
    const float* rb = xb + (size_t)snb*256;
    float xa0=ra[0], xa1=ra[64], xa2=ra[128], xa3=ra[192];
    float xb0=rb[0], xb1=rb[64], xb2=rb[128], xb3=rb[192];
    float pa0=__expf(lrelu(ea.x+ad.x)), pa1=__expf(lrelu(ea.y+ad.y));
    float pa2=__expf(lrelu(ea.z+ad.z)), pa3=__expf(lrelu(ea.w+ad.w));
    float pb0=__expf(lrelu(eb.x+ad.x)), pb1=__expf(lrelu(eb.y+ad.y));
    float pb2=__expf(lrelu(eb.z+ad.z)), pb3=__expf(lrelu(eb.w+ad.w));
    s0 += pa0 + pb0; a0 += pa0*xa0 + pb0*xb0;
    s1 += pa1 + pb1; a1 += pa1*xa1 + pb1*xb1;
    s2 += pa2 + pb2; a2 += pa2*xa2 + pb2*xb2;
    s3 += pa3 + pb3; a3 += pa3*xa3 + pb3*xb3;
  }
  for (; j < re; ++j){
    int sn = csr[j];
    float4 ev = ((const float4*)a_src)[sn];
    const float* r = xb + (size_t)sn*256;
    float p0=__expf(lrelu(ev.x+ad.x)), p1=__expf(lrelu(ev.y+ad.y));
    float p2=__expf(lrelu(ev.z+ad.z)), p3=__expf(lrelu(ev.w+ad.w));
    s0 += p0; a0 += p0*r[0];
    s1 += p1; a1 += p1*r[64];
    s2 += p2; a2 += p2*r[128];
    s3 += p3; a3 += p3*r[192];
  }
  float o = 0.25f*(a0/(s0+1e-16f) + a1/(s1+1e-16f) + a2/(s2+1e-16f) + a3/(s3+1e-16f));
  ht[(size_t)n*64 + lane] = eluf(o + b2[lane]);
}

// ---------------- fused temporal conv stack + MLP, 4 nodes per wave ----------------
__global__ __launch_bounds__(256) void k_temporal(
    const float* __restrict__ htb,
    const float4* __restrict__ w1p, const float* __restrict__ cb1,
    const float* __restrict__ g1,   const float* __restrict__ be1,
    const float4* __restrict__ w2p, const float* __restrict__ cb2,
    const float* __restrict__ g2,   const float* __restrict__ be2,
    const float* __restrict__ lw1,  const float* __restrict__ lb1,
    const float* __restrict__ lw2,  const float* __restrict__ lb2,
    float* __restrict__ out){
  __shared__ float X[16][64][8];   // [node-in-block][chan][time(padded)] = 32 KB
  int o   = threadIdx.x & 63;
  int wid = threadIdx.x >> 6;
  int nb0 = blockIdx.x*16;        // 3125*16 == 50000 exactly

#pragma unroll
  for (int q = 0; q < 4; ++q){
    int bnn = wid*4 + q;
    int n = nb0 + bnn;
    X[bnn][o][0] = 0.f; X[bnn][o][7] = 0.f;
#pragma unroll
    for (int t = 0; t < 6; ++t) X[bnn][o][t+1] = htb[((size_t)t*NN + n)*64 + o];
  }
  __syncthreads();

  float acc[4][6];
  // ---- conv1 ----
  {
    float c = cb1[o];
#pragma unroll
    for (int q = 0; q < 4; ++q)
#pragma unroll
      for (int t = 0; t < 6; ++t) acc[q][t] = c;
    for (int i = 0; i < 64; ++i){
      float4 w = w1p[i*64 + o];
#pragma unroll
      for (int q = 0; q < 4; ++q){
        int bnn = wid*4 + q;
        float4 xa = *(const float4*)&X[bnn][i][0];
        float4 xc = *(const float4*)&X[bnn][i][4];
        acc[q][0] += w.x*xa.x + w.y*xa.y + w.z*xa.z;
        acc[q][1] += w.x*xa.y + w.y*xa.z + w.z*xa.w;
        acc[q][2] += w.x*xa.z + w.y*xa.w + w.z*xc.x;
        acc[q][3] += w.x*xa.w + w.y*xc.x + w.z*xc.y;
        acc[q][4] += w.x*xc.x + w.y*xc.y + w.z*xc.z;
        acc[q][5] += w.x*xc.y + w.y*xc.z + w.z*xc.w;
      }
    }
    float bns = g1[o]*rsqrtf(1.f + 1e-5f), be = be1[o];
    __syncthreads();
#pragma unroll
    for (int q = 0; q < 4; ++q)
#pragma unroll
      for (int t = 0; t < 6; ++t) X[wid*4+q][o][t+1] = fmaxf(acc[q][t]*bns + be, 0.f);
    __syncthreads();
  }
  // ---- conv2 + pool ----
  {
    float c = cb2[o];
#pragma unroll
    for (int q = 0; q < 4; ++q)
#pragma unroll
      for (int t = 0; t < 6; ++t) acc[q][t] = c;
    for (int i = 0; i < 64; ++i){
      float4 w = w2p[i*64 + o];
#pragma unroll
      for (int q = 0; q < 4; ++q){
        int bnn = wid*4 + q;
        float4 xa = *(const float4*)&X[bnn][i][0];
        float4 xc = *(const float4*)&X[bnn][i][4];
        acc[q][0] += w.x*xa.x + w.y*xa.y + w.z*xa.z;
        acc[q][1] += w.x*xa.y + w.y*xa.z + w.z*xa.w;
        acc[q][2] += w.x*xa.z + w.y*xa.w + w.z*xc.x;
        acc[q][3] += w.x*xa.w + w.y*xc.x + w.z*xc.y;
        acc[q][4] += w.x*xc.x + w.y*xc.y + w.z*xc.z;
        acc[q][5] += w.x*xc.y + w.y*xc.z + w.z*xc.w;
      }
    }
    float bns = g2[o]*rsqrtf(1.f + 1e-5f), be = be2[o];
    __syncthreads();
#pragma unroll
    for (int q = 0; q < 4; ++q){
      float pooled = 0.f;
#pragma unroll
      for (int t = 0; t < 6; ++t) pooled += fmaxf(acc[q][t]*bns + be, 0.f);
      X[wid*4+q][o][0] = pooled*(1.f/6.f);
    }
    __syncthreads();
  }
  // ---- MLP: lanes 0-31 do even node, 32-63 odd node of each pair ----
  {
    int jj   = threadIdx.x & 31;
    int half = (o >> 5);
    float w2v = lw2[jj];
    float lb  = lb1[jj];
#pragma unroll
    for (int pr = 0; pr < 2; ++pr){
      int bnn = wid*4 + pr*2 + half;
      float a = lb;
      for (int k = 0; k < 64; ++k) a += X[bnn][k][0] * lw1[k*32 + jj];
      float part = fmaxf(a, 0.f) * w2v;
#pragma unroll
      for (int off = 16; off >= 1; off >>= 1) part += __shfl_xor(part, off);
      if (jj == 0) out[nb0 + bnn] = part + lb2[0];
    }
  }
}

// ---------------- launch ----------------
extern "C" void kernel_launch(void* const* d_in, const int* in_sizes, int n_in,
                              void* d_out, int out_size, void* d_ws, size_t ws_size,
                              hipStream_t stream) {
  const float* x_seq = (const float*)d_in[0];
  const int*   ei    = (const int*)  d_in[1];
  const float* W1  = (const float*)d_in[2];
  const float* as1 = (const float*)d_in[3];
  const float* ad1 = (const float*)d_in[4];
  const float* b1  = (const float*)d_in[5];
  const float* W2  = (const float*)d_in[6];
  const float* as2 = (const float*)d_in[7];
  const float* ad2 = (const float*)d_in[8];
  const float* b2  = (const float*)d_in[9];
  const float* cw1 = (const float*)d_in[10];
  const float* cb1 = (const float*)d_in[11];
  const float* g1  = (const float*)d_in[12];
  const float* be1 = (const float*)d_in[13];
  const float* cw2 = (const float*)d_in[14];
  const float* cb2 = (const float*)d_in[15];
  const float* g2  = (const float*)d_in[16];
  const float* be2 = (const float*)d_in[17];
  const float* lw1 = (const float*)d_in[18];
  const float* lb1 = (const float*)d_in[19];
  const float* lw2 = (const float*)d_in[20];
  const float* lb2 = (const float*)d_in[21];
  float* out = (float*)d_out;

  char* wp = (char*)d_ws;
  auto alloc = [&](size_t bytes) -> char* {
    char* p = wp; wp += (bytes + 255) & ~(size_t)255; return p;
  };
  int*   counts = (int*)  alloc(NN*sizeof(int));
  int*   excl   = (int*)  alloc(NN*sizeof(int));
  int*   bsum   = (int*)  alloc(64*sizeof(int));
  int*   rowptr = (int*)  alloc((NN+1)*sizeof(int));
  int*   cursor = (int*)  alloc(NN*sizeof(int));
  int*   csr    = (int*)  alloc((size_t)(EE+NN)*sizeof(int));
  float* a_src  = (float*)alloc((size_t)NN*4*sizeof(float));
  float* a_dst  = (float*)alloc((size_t)NN*4*sizeof(float));
  float* xl     = (float*)alloc((size_t)NN*256*sizeof(float));
  float* h1     = (float*)alloc((size_t)NN*64*sizeof(float));
  float* htb    = (float*)alloc((size_t)TT*NN*64*sizeof(float));
  float* Was1   = (float*)alloc(256*sizeof(float));
  float* Wad1   = (float*)alloc(256*sizeof(float));
  float* Was2   = (float*)alloc(256*sizeof(float));
  float* Wad2   = (float*)alloc(256*sizeof(float));
  float4* w1p   = (float4*)alloc(64*64*sizeof(float4));
  float4* w2p   = (float4*)alloc(64*64*sizeof(float4));

  const int NBSCAN = (NN + 1023)/1024;   // 49
  k_init_counts<<<(NN+255)/256, 256, 0, stream>>>(counts);
  k_hist<<<(EE+255)/256, 256, 0, stream>>>(ei + EE, counts);
  k_scanA<<<NBSCAN, 1024, 0, stream>>>(counts, excl, bsum);
  k_scanB<<<1, 64, 0, stream>>>(bsum, NBSCAN);
  k_scanC<<<NBSCAN, 1024, 0, stream>>>(excl, bsum, rowptr, cursor);
  k_scatter<<<(EE+NN+255)/256, 256, 0, stream>>>(ei, cursor, csr);
  k_prep<<<1, 256, 0, stream>>>(W1, as1, ad1, W2, as2, ad2, cw1, cw2,
                                Was1, Wad1, Was2, Wad2, w1p, w2p);

  for (int t = 0; t < TT; ++t){
    k_gemm_att<64><<<NN/16, 256, 0, stream>>>(x_seq + (size_t)t*NN*64, W1, Was1, Wad1,
                                              xl, a_src, a_dst);
    k_agg1<<<NN/4, 256, 0, stream>>>(xl, a_src, a_dst, b1, rowptr, csr, h1);
    k_gemm_att<256><<<NN/16, 256, 0, stream>>>(h1, W2, Was2, Wad2, xl, a_src, a_dst);
    k_agg2<<<NN/4, 256, 0, stream>>>(xl, a_src, a_dst, b2, rowptr, csr,
                                     htb + (size_t)t*NN*64);
  }
  k_temporal<<<NN/16, 256, 0, stream>>>(htb, w1p, cb1, g1, be1, w2p, cb2, g2, be2,
                                        lw1, lb1, lw2, lb2, out);
}